// Round 3
// baseline (809.722 us; speedup 1.0000x reference)
//
#include <hip/hip_runtime.h>

// ViTWarpFWarp R3: scatter->gather inversion with fused epilogue.
//   - contributor lists per output pixel (channel-independent)
//   - img transposed to (N,HW,C): contributor reads are 512B contiguous
//   - gather_direct: block = 64 output pixels x 128 channels; accumulate in
//     registers, restage via padded LDS, write BOTH outputs directly in final
//     (N,C,H,W) layout (coalesced 256B rows). No transpose-back, no ones
//     broadcast, no output memset (every element is written).

constexpr int N_ = 4, C_ = 128, H_ = 216, W_ = 384;
constexpr int HW    = H_ * W_;            // 82944
constexpr int TOTAL = N_ * C_ * HW;       // 42467328
constexpr int PIX   = N_ * HW;            // 331776
constexpr int SCAN_BLOCKS = PIX / 256;    // 1296

// ---------------- workspace layout (4-byte elements) ----------------
constexpr size_t OFF_IMGT   = 0;                       // TOTAL floats
constexpr size_t OFF_COUNTS = (size_t)TOTAL;           // PIX uint
constexpr size_t OFF_CURSOR = OFF_COUNTS + PIX;        // PIX uint
constexpr size_t OFF_OFFS   = OFF_CURSOR + PIX;        // PIX uint
constexpr size_t OFF_BS     = OFF_OFFS + PIX;          // 4096 uint
constexpr size_t OFF_ES     = OFF_BS + 4096;           // 4*PIX uint
constexpr size_t OFF_EW     = OFF_ES + 4ull * PIX;     // 4*PIX float
constexpr size_t WS_ELEMS   = OFF_EW + 4ull * PIX;
constexpr size_t WS_BYTES   = WS_ELEMS * 4;

__device__ inline void corner_math(float fx, float fy, int& ifx, int& ify,
                                   float& ex0, float& ex1, float& ey0, float& ey1) {
    float fx1 = floorf(fx), fy1 = floorf(fy);
    float dx = fx - fx1, dy = fy - fy1;
    ifx = (int)fx1; ify = (int)fy1;
    ex0 = __expf(-dx * dx);
    ex1 = __expf(-(dx - 1.f) * (dx - 1.f));
    ey0 = __expf(-dy * dy);
    ey1 = __expf(-(dy - 1.f) * (dy - 1.f));
}

// ---------------- pass 0: transpose img (C,HW) -> (HW,C) per batch ----------
__global__ __launch_bounds__(256) void transpose_fwd_k(const float* __restrict__ img,
                                                       float* __restrict__ imgT) {
    __shared__ float tile[32][33];
    int n   = blockIdx.z;
    int hw0 = blockIdx.x * 32;
    int c0  = blockIdx.y * 32;
    const float* src = img  + (size_t)n * C_ * HW;
    float*       dst = imgT + (size_t)n * HW * C_;
    int tx = threadIdx.x, ty = threadIdx.y;
#pragma unroll
    for (int r = 0; r < 32; r += 8)
        tile[ty + r][tx] = src[(size_t)(c0 + ty + r) * HW + hw0 + tx];
    __syncthreads();
#pragma unroll
    for (int r = 0; r < 32; r += 8)
        dst[(size_t)(hw0 + ty + r) * C_ + c0 + tx] = tile[tx][ty + r];
}

// ---------------- pass 1: count contributors per target ----------------
__global__ __launch_bounds__(256) void count_k(const float* __restrict__ flo,
                                               unsigned int* __restrict__ counts) {
    int idx = blockIdx.x * 256 + threadIdx.x;
    if (idx >= PIX) return;
    int s = idx % HW, n = idx / HW;
    int h = s / W_, w = s % W_;
    float fy = flo[(n * 2 + 0) * HW + s];
    float fx = flo[(n * 2 + 1) * HW + s];
    int ifx, ify; float ex0, ex1, ey0, ey1;
    corner_math(fx, fy, ifx, ify, ex0, ex1, ey0, ey1);
    int ix = h + ifx, iy = w + ify;
    unsigned int* base = counts + (size_t)n * HW;
    bool bx0 = (unsigned)ix       < (unsigned)H_;
    bool bx1 = (unsigned)(ix + 1) < (unsigned)H_;
    bool by0 = (unsigned)iy       < (unsigned)W_;
    bool by1 = (unsigned)(iy + 1) < (unsigned)W_;
    if (bx0 && by0) atomicAdd(base + ix * W_ + iy, 1u);
    if (bx0 && by1) atomicAdd(base + ix * W_ + iy + 1, 1u);
    if (bx1 && by0) atomicAdd(base + (ix + 1) * W_ + iy, 1u);
    if (bx1 && by1) atomicAdd(base + (ix + 1) * W_ + iy + 1, 1u);
}

// ---------------- pass 2: exclusive scan (block-local + blocksum scan) ------
__global__ __launch_bounds__(256) void scan_local_k(const unsigned int* __restrict__ counts,
                                                    unsigned int* __restrict__ offs,
                                                    unsigned int* __restrict__ bs) {
    __shared__ unsigned int tmp[256];
    int tid = threadIdx.x;
    int i = blockIdx.x * 256 + tid;
    unsigned int v = counts[i];
    tmp[tid] = v;
    __syncthreads();
    for (int off = 1; off < 256; off <<= 1) {
        unsigned int t = (tid >= off) ? tmp[tid - off] : 0u;
        __syncthreads();
        tmp[tid] += t;
        __syncthreads();
    }
    offs[i] = tmp[tid] - v;                 // exclusive within block
    if (tid == 255) bs[blockIdx.x] = tmp[tid];
}

__global__ __launch_bounds__(256) void scan_bs_k(unsigned int* __restrict__ bs) {
    __shared__ unsigned int tmp[256];
    constexpr int IT = 6;                    // 256*6 >= 1296
    int tid = threadIdx.x;
    unsigned int v[IT]; unsigned int sum = 0;
#pragma unroll
    for (int i = 0; i < IT; ++i) {
        int j = tid * IT + i;
        v[i] = (j < SCAN_BLOCKS) ? bs[j] : 0u;
        sum += v[i];
    }
    tmp[tid] = sum;
    __syncthreads();
    for (int off = 1; off < 256; off <<= 1) {
        unsigned int t = (tid >= off) ? tmp[tid - off] : 0u;
        __syncthreads();
        tmp[tid] += t;
        __syncthreads();
    }
    unsigned int run = tmp[tid] - sum;       // exclusive
#pragma unroll
    for (int i = 0; i < IT; ++i) {
        int j = tid * IT + i;
        if (j < SCAN_BLOCKS) { unsigned int old = v[i]; bs[j] = run; run += old; }
    }
}

// ---------------- pass 3: fill entries (offset = offs + bs) ----------------
__global__ __launch_bounds__(256) void fill_k(const float* __restrict__ flo,
                                              const unsigned int* __restrict__ offs,
                                              const unsigned int* __restrict__ bs,
                                              unsigned int* __restrict__ cursor,
                                              unsigned int* __restrict__ entry_s,
                                              float* __restrict__ entry_w) {
    int idx = blockIdx.x * 256 + threadIdx.x;
    if (idx >= PIX) return;
    int s = idx % HW, n = idx / HW;
    int h = s / W_, w = s % W_;
    float fy = flo[(n * 2 + 0) * HW + s];
    float fx = flo[(n * 2 + 1) * HW + s];
    int ifx, ify; float ex0, ex1, ey0, ey1;
    corner_math(fx, fy, ifx, ify, ex0, ex1, ey0, ey1);
    int ix = h + ifx, iy = w + ify;
    bool bx[2] = { (unsigned)ix < (unsigned)H_, (unsigned)(ix + 1) < (unsigned)H_ };
    bool by[2] = { (unsigned)iy < (unsigned)W_, (unsigned)(iy + 1) < (unsigned)W_ };
    float exw[2] = { ex0, ex1 }, eyw[2] = { ey0, ey1 };
#pragma unroll
    for (int a = 0; a < 2; ++a) {
#pragma unroll
        for (int b = 0; b < 2; ++b) {
            if (bx[a] && by[b]) {
                int t = n * HW + (ix + a) * W_ + (iy + b);
                unsigned int slot = atomicAdd(cursor + t, 1u);
                unsigned int e = offs[t] + bs[t >> 8] + slot;
                entry_s[e] = (unsigned int)s;
                entry_w[e] = exw[a] * eyw[b];
            }
        }
    }
}

// ---------------- pass 4: gather + fused epilogue ----------------
// block: 64 consecutive output pixels x 128 channels.
// phase 1: 8 pixel-slots x 32 float4-lanes, accumulate over contributors.
// phase 2: restage via padded LDS, write img_warp and one_warp in final
//          (N,C,H,W) layout with 256B-contiguous rows.
__global__ __launch_bounds__(256) void gather_direct_k(
        const float* __restrict__ imgT,
        const unsigned int* __restrict__ counts,
        const unsigned int* __restrict__ offs,
        const unsigned int* __restrict__ bs,
        const unsigned int* __restrict__ entry_s,
        const float* __restrict__ entry_w,
        float* __restrict__ out_img,
        float* __restrict__ out_ones) {
    __shared__ float tile[64][129];          // +1 pad: phase-2 reads conflict-free
    __shared__ float onesb[64];
    int tid = threadIdx.x;
    int pl  = tid >> 5;                      // pixel slot 0..7
    int cg  = tid & 31;                      // float4 channel group
    int t0  = blockIdx.x * 64;               // HW % 64 == 0 -> never crosses n
    int n   = t0 / HW;
    int p0  = t0 - n * HW;
    const float4* srcBase = (const float4*)(imgT + (size_t)n * HW * C_);
    for (int j = 0; j < 8; ++j) {
        int px = j * 8 + pl;
        int t  = t0 + px;
        unsigned int k   = counts[t];
        unsigned int off = offs[t] + bs[t >> 8];
        float4 acc = make_float4(0.f, 0.f, 0.f, 0.f);
        float wsum = 0.f;
        for (unsigned int e = 0; e < k; ++e) {
            unsigned int s = entry_s[off + e];
            float wgt     = entry_w[off + e];
            float4 v = srcBase[(size_t)s * (C_ / 4) + cg];
            acc.x += wgt * v.x; acc.y += wgt * v.y;
            acc.z += wgt * v.z; acc.w += wgt * v.w;
            wsum += wgt;
        }
        tile[px][cg * 4 + 0] = acc.x;
        tile[px][cg * 4 + 1] = acc.y;
        tile[px][cg * 4 + 2] = acc.z;
        tile[px][cg * 4 + 3] = acc.w;
        if (cg == 0) onesb[px] = wsum;
    }
    __syncthreads();
    int i  = tid & 63;                       // pixel within tile
    int cq = tid >> 6;                       // 0..3 channel sub-slot
    float onev = onesb[i];
#pragma unroll
    for (int cb = 0; cb < 32; ++cb) {
        int c = cb * 4 + cq;
        float v = tile[i][c];                // banks (129*i+c)%32: 2-way, free
        size_t base = (size_t)(n * C_ + c) * HW + p0 + i;
        out_img[base]  = v;
        out_ones[base] = onev;
    }
}

// ================= R1 fallback (atomic scatter) =================
__global__ __launch_bounds__(256) void fb_scatter_k(const float* __restrict__ img,
                                                    const float* __restrict__ flo,
                                                    float* __restrict__ out_img,
                                                    float* __restrict__ out_ones) {
    int idx = blockIdx.x * 256 + threadIdx.x;
    if (idx >= TOTAL) return;
    int w = idx % W_; int rem = idx / W_; int h = rem % H_; rem /= H_;
    int c = rem % C_; int n = rem / C_;
    float fy = flo[(n * 2 + 0) * HW + h * W_ + w];
    float fx = flo[(n * 2 + 1) * HW + h * W_ + w];
    int ifx, ify; float ex0, ex1, ey0, ey1;
    corner_math(fx, fy, ifx, ify, ex0, ex1, ey0, ey1);
    int ix = h + ifx, iy = w + ify;
    float v = img[idx];
    float* pi = out_img  + (size_t)(n * C_ + c) * HW;
    float* po = out_ones + (size_t)(n * C_ + c) * HW;
    if ((unsigned)ix < (unsigned)H_ && (unsigned)iy < (unsigned)W_) {
        atomicAdd(pi + ix * W_ + iy, v * ex0 * ey0);
        atomicAdd(po + ix * W_ + iy, ex0 * ey0);
    }
    if ((unsigned)ix < (unsigned)H_ && (unsigned)(iy + 1) < (unsigned)W_) {
        atomicAdd(pi + ix * W_ + iy + 1, v * ex0 * ey1);
        atomicAdd(po + ix * W_ + iy + 1, ex0 * ey1);
    }
    if ((unsigned)(ix + 1) < (unsigned)H_ && (unsigned)iy < (unsigned)W_) {
        atomicAdd(pi + (ix + 1) * W_ + iy, v * ex1 * ey0);
        atomicAdd(po + (ix + 1) * W_ + iy, ex1 * ey0);
    }
    if ((unsigned)(ix + 1) < (unsigned)H_ && (unsigned)(iy + 1) < (unsigned)W_) {
        atomicAdd(pi + (ix + 1) * W_ + iy + 1, v * ex1 * ey1);
        atomicAdd(po + (ix + 1) * W_ + iy + 1, ex1 * ey1);
    }
}

// ================= launch =================
extern "C" void kernel_launch(void* const* d_in, const int* in_sizes, int n_in,
                              void* d_out, int out_size, void* d_ws, size_t ws_size,
                              hipStream_t stream) {
    const float* img = (const float*)d_in[0];
    const float* flo = (const float*)d_in[1];
    float* out      = (float*)d_out;
    float* out_img  = out;
    float* out_ones = out + (size_t)TOTAL;

    if (ws_size < WS_BYTES) {
        hipMemsetAsync(out, 0, 2ull * TOTAL * sizeof(float), stream);
        fb_scatter_k<<<(TOTAL + 255) / 256, 256, 0, stream>>>(img, flo, out_img, out_ones);
        return;
    }

    float* ws = (float*)d_ws;
    float*        imgT    = ws + OFF_IMGT;
    unsigned int* counts  = (unsigned int*)(ws + OFF_COUNTS);
    unsigned int* cursor  = (unsigned int*)(ws + OFF_CURSOR);
    unsigned int* offs    = (unsigned int*)(ws + OFF_OFFS);
    unsigned int* bs      = (unsigned int*)(ws + OFF_BS);
    unsigned int* entry_s = (unsigned int*)(ws + OFF_ES);
    float*        entry_w = ws + OFF_EW;

    // zero counts + cursor (contiguous, 2.65 MB)
    hipMemsetAsync(counts, 0, 2ull * PIX * sizeof(unsigned int), stream);

    dim3 tb(32, 8);
    transpose_fwd_k<<<dim3(HW / 32, C_ / 32, N_), tb, 0, stream>>>(img, imgT);
    count_k<<<SCAN_BLOCKS, 256, 0, stream>>>(flo, counts);
    scan_local_k<<<SCAN_BLOCKS, 256, 0, stream>>>(counts, offs, bs);
    scan_bs_k<<<1, 256, 0, stream>>>(bs);
    fill_k<<<SCAN_BLOCKS, 256, 0, stream>>>(flo, offs, bs, cursor, entry_s, entry_w);
    gather_direct_k<<<PIX / 64, 256, 0, stream>>>(imgT, counts, offs, bs,
                                                  entry_s, entry_w, out_img, out_ones);
}